// Round 1
// baseline (370.987 us; speedup 1.0000x reference)
//
#include <hip/hip_runtime.h>
#include <math.h>

#define E_DIM 128
#define R_DIM 128
#define N_REL 64
#define REG_LAMBDA 1e-5f

#define NSEG 32      // segments per relation -> grid = 64*32 = 2048 blocks
#define GMAX 8       // samples processed per chunk (register-tiled)
#define LISTMAX 512  // >= ceil(M/NSEG) worst case (M=8192 -> 256)

// Relation-grouped kernel. Block b handles relation (b>>5) over sample range
// [seg*range, (seg+1)*range). Each streamed W element feeds 3*GMAX FMAs.
// Thread t (0..127) owns output column t. Per-sample arithmetic is kept
// bitwise identical to the previous passing kernel (same e-order, same
// shuffle-reduce order, same softplus formula).
__global__ void __launch_bounds__(128)
kge_grouped_kernel(const int* __restrict__ h_idx, const int* __restrict__ r_idx,
                   const int* __restrict__ pt_idx, const int* __restrict__ nt_idx,
                   const float* __restrict__ ent,   // (N_ENT, 128)
                   const float* __restrict__ rel,   // (64, 128)
                   const float* __restrict__ W,     // (64, 128, 128)
                   float* __restrict__ per_sample,  // (M,)
                   int M)
{
    const int t      = threadIdx.x;          // 0..127
    const int rel_id = blockIdx.x >> 5;      // 0..63
    const int seg    = blockIdx.x & (NSEG - 1);

    __shared__ int s_cnt;
    __shared__ int s_list[LISTMAX];
    __shared__ __align__(16) float sh[GMAX][E_DIM];
    __shared__ __align__(16) float sp[GMAX][E_DIM];
    __shared__ __align__(16) float sn[GMAX][E_DIM];
    __shared__ float wpart[3][GMAX][2];

    const int range = (M + NSEG - 1) / NSEG;
    const int m0 = seg * range;
    const int m1 = min(m0 + range, M);

    // ---- scan my slice of r[] for samples with my relation ----
    if (t == 0) s_cnt = 0;
    __syncthreads();
    for (int m = m0 + t; m < m1; m += 128) {
        if (r_idx[m] == rel_id) {
            int p = atomicAdd(&s_cnt, 1);
            s_list[p] = m;
        }
    }
    __syncthreads();
    const int cnt = s_cnt;
    if (cnt == 0) return;

    const float* __restrict__ Wr = W + (size_t)rel_id * (E_DIM * R_DIM);
    const float re = rel[(size_t)rel_id * R_DIM + t];

    for (int c0 = 0; c0 < cnt; c0 += GMAX) {
        // ---- stage up to GMAX sample triples into LDS (pads dup last valid) ----
#pragma unroll
        for (int g = 0; g < GMAX; ++g) {
            int sl = c0 + g; if (sl > cnt - 1) sl = cnt - 1;
            int m = s_list[sl];
            sh[g][t] = ent[(size_t)h_idx[m]  * E_DIM + t];
            sp[g][t] = ent[(size_t)pt_idx[m] * E_DIM + t];
            sn[g][t] = ent[(size_t)nt_idx[m] * E_DIM + t];
        }
        __syncthreads();

        float ah[GMAX], ap[GMAX], an[GMAX];
#pragma unroll
        for (int g = 0; g < GMAX; ++g) { ah[g] = 0.f; ap[g] = 0.f; an[g] = 0.f; }

        // ---- main loop: each W element feeds 3*GMAX FMAs ----
#pragma unroll 2
        for (int e0 = 0; e0 < E_DIM; e0 += 4) {
            float w0 = Wr[(size_t)(e0 + 0) * R_DIM + t];
            float w1 = Wr[(size_t)(e0 + 1) * R_DIM + t];
            float w2 = Wr[(size_t)(e0 + 2) * R_DIM + t];
            float w3 = Wr[(size_t)(e0 + 3) * R_DIM + t];
#pragma unroll
            for (int g = 0; g < GMAX; ++g) {
                float4 h4 = *(const float4*)&sh[g][e0];
                float4 p4 = *(const float4*)&sp[g][e0];
                float4 n4 = *(const float4*)&sn[g][e0];
                ah[g] = fmaf(h4.x, w0, ah[g]); ah[g] = fmaf(h4.y, w1, ah[g]);
                ah[g] = fmaf(h4.z, w2, ah[g]); ah[g] = fmaf(h4.w, w3, ah[g]);
                ap[g] = fmaf(p4.x, w0, ap[g]); ap[g] = fmaf(p4.y, w1, ap[g]);
                ap[g] = fmaf(p4.z, w2, ap[g]); ap[g] = fmaf(p4.w, w3, ap[g]);
                an[g] = fmaf(n4.x, w0, an[g]); an[g] = fmaf(n4.y, w1, an[g]);
                an[g] = fmaf(n4.z, w2, an[g]); an[g] = fmaf(n4.w, w3, an[g]);
            }
        }

        // ---- epilogue: per-slot reductions (identical order to old kernel) ----
#pragma unroll
        for (int g = 0; g < GMAX; ++g) {
            float he = sh[g][t], pe = sp[g][t], ne = sn[g][t];
            float a  = ah[g] + re;
            float dp = a - ap[g];
            float dn = a - an[g];
            float pos = dp * dp;
            float neg = dn * dn;
            float reg = he * he + re * re + pe * pe + ne * ne;
#pragma unroll
            for (int off = 32; off > 0; off >>= 1) {
                pos += __shfl_down(pos, off);
                neg += __shfl_down(neg, off);
                reg += __shfl_down(reg, off);
            }
            if ((t & 63) == 0) {
                int wv = t >> 6;
                wpart[0][g][wv] = pos; wpart[1][g][wv] = neg; wpart[2][g][wv] = reg;
            }
        }
        __syncthreads();
        if (t < GMAX && (c0 + t) < cnt) {
            float P = wpart[0][t][0] + wpart[0][t][1];
            float N = wpart[1][t][0] + wpart[1][t][1];
            float R = wpart[2][t][0] + wpart[2][t][1];
            float diff = 0.5f * (P - N);            // pos_score - neg_score
            float z = -diff;                        // -log_sigmoid(diff) = softplus(-diff)
            float sp_v = fmaxf(z, 0.f) + log1pf(expf(-fabsf(z)));
            per_sample[s_list[c0 + t]] = sp_v + REG_LAMBDA * 0.5f * R;
        }
        // no extra barrier needed: next chunk's staging only writes sh/sp/sn
        // (not read by the t<GMAX finalize), and its first wpart store is
        // behind the staging __syncthreads().
    }
}

// Single-block final reduction -> mean (unchanged; bitwise identical)
__global__ void __launch_bounds__(256)
kge_reduce_kernel(const float* __restrict__ per_sample, float* __restrict__ out, int M)
{
    int t = threadIdx.x;
    float s = 0.f;
    for (int i = t; i < M; i += 256) s += per_sample[i];
#pragma unroll
    for (int off = 32; off > 0; off >>= 1) s += __shfl_down(s, off);
    __shared__ float part[4];
    if ((t & 63) == 0) part[t >> 6] = s;
    __syncthreads();
    if (t == 0) out[0] = (part[0] + part[1] + part[2] + part[3]) / (float)M;
}

extern "C" void kernel_launch(void* const* d_in, const int* in_sizes, int n_in,
                              void* d_out, int out_size, void* d_ws, size_t ws_size,
                              hipStream_t stream)
{
    const int*   h_idx  = (const int*)d_in[0];
    const int*   r_idx  = (const int*)d_in[1];
    const int*   pt_idx = (const int*)d_in[2];
    const int*   nt_idx = (const int*)d_in[3];
    const float* ent    = (const float*)d_in[4];
    const float* rel    = (const float*)d_in[5];
    const float* W      = (const float*)d_in[6];
    float* out = (float*)d_out;

    int M = in_sizes[0];
    float* per_sample = (float*)d_ws;  // M floats

    kge_grouped_kernel<<<N_REL * NSEG, 128, 0, stream>>>(h_idx, r_idx, pt_idx, nt_idx,
                                                         ent, rel, W, per_sample, M);
    kge_reduce_kernel<<<1, 256, 0, stream>>>(per_sample, out, M);
}